// Round 3
// baseline (1662.967 us; speedup 1.0000x reference)
//
#include <hip/hip_runtime.h>
#include <stdint.h>
#include <math.h>

// ---------------------------------------------------------------------------
// MultiScaleResidualQuantizer3D  (B=128, C=32, HW=16, N_E=4096, 10 scales)
// Round 2: occupancy + structure.
//   - quant SEG per scale so grid >= 1024 blocks (was 1 blk/CU -> 4-7 blk/CU)
//   - conv split into 4-row quarters (grid 512), LDS overlay h0/partial,
//     epilogue across all 4 waves, hist folded into last conv
//   - setup: memset+cbn+wT+bicubic merged into one kernel
//   - PHI_IDX = [0,0,0,1,1,2,2,2,3,3] (exact np.linspace tie resolution)
// ---------------------------------------------------------------------------

#define DEVI __device__ __forceinline__

static constexpr int NE = 4096;

typedef _Float16 half8 __attribute__((ext_vector_type(8)));
typedef float floatx4 __attribute__((ext_vector_type(4)));

DEVI unsigned fkey(float f) {
    unsigned u = __float_as_uint(f);
    return (u & 0x80000000u) ? ~u : (u | 0x80000000u);  // order-preserving
}
DEVI unsigned long long packSI(float s, unsigned idx) {
    // high: monotone score key; low: ~idx so ties prefer SMALLER idx (first max)
    return ((unsigned long long)fkey(s) << 32) | (unsigned)(~idx);
}
DEVI int unpackI(unsigned long long v) {
    return (int)(~(unsigned)(v & 0xFFFFFFFFull));
}
DEVI unsigned long long shflx(unsigned long long v, int m) {
    unsigned lo = (unsigned)v, hi = (unsigned)(v >> 32);
    lo = __shfl_xor(lo, m, 64);
    hi = __shfl_xor(hi, m, 64);
    return ((unsigned long long)hi << 32) | lo;
}

// --------------------------- setup kernel ----------------------------------
// blocks 0..15: codebook normalize + fp16 hi/lo split
// blocks 16..159: wT transpose  wT[k][(ic*9+ky*3+kx)][oc]
// block 160: bicubic U matrices (f64 math) + zero lossAcc/hist
// blocks 161..1184: zero fhat
__global__ void __launch_bounds__(256) k_setup(const float* __restrict__ cb,
                                               const float* __restrict__ pw,
                                               _Float16* __restrict__ cbh,
                                               _Float16* __restrict__ cbl,
                                               float* __restrict__ wT,
                                               float* __restrict__ um,
                                               float* __restrict__ fhat,
                                               float* __restrict__ lossAcc) {
    int blk = blockIdx.x, tid = threadIdx.x;
    if (blk < 16) {
        int r = blk * 256 + tid;
        const float* src = cb + r * 32;
        float v[32];
        float ss = 0.f;
#pragma unroll
        for (int j = 0; j < 32; ++j) { v[j] = src[j]; ss += v[j] * v[j]; }
        float n = fmaxf(sqrtf(ss), 1e-12f);
#pragma unroll
        for (int j = 0; j < 32; ++j) {
            float x = v[j] / n;
            _Float16 h = (_Float16)x;
            cbh[r * 32 + j] = h;
            cbl[r * 32 + j] = (_Float16)(x - (float)h);
        }
    } else if (blk < 160) {
        int e = (blk - 16) * 256 + tid;             // < 36864
        int k = e / 9216, rem = e % 9216;
        int s = rem / 32, oc = rem % 32;
        int ic = s / 9, k9 = s % 9, ky = k9 / 3, kx = k9 % 3;
        wT[e] = pw[(((k * 32 + oc) * 32 + ic) * 3 + ky) * 3 + kx];
    } else if (blk == 160) {
        if (tid < 144) {
            const int pns[9] = {1, 2, 3, 4, 5, 6, 8, 10, 13};
            int si = tid / 16, y = tid % 16, pn = pns[si];
            double scale = (double)pn / 16.0;
            double src = ((double)y + 0.5) * scale - 0.5;
            double fl = floor(src);
            int i0 = (int)fl;
            double f = src - fl;
            float row[13];
            for (int j = 0; j < pn; ++j) row[j] = 0.f;
            const double a = -0.75;
#pragma unroll
            for (int off = -1; off <= 2; ++off) {
                double t2 = fabs(f - (double)off);
                double wgt;
                if (t2 <= 1.0)      wgt = ((a + 2.0) * t2 - (a + 3.0)) * t2 * t2 + 1.0;
                else if (t2 < 2.0)  wgt = (((t2 - 5.0) * t2 + 8.0) * t2 - 4.0) * a;
                else                wgt = 0.0;
                int j = i0 + off;
                j = j < 0 ? 0 : (j > pn - 1 ? pn - 1 : j);
                row[j] = (float)((double)row[j] + wgt);   // numpy f32 += f64
            }
            for (int j = 0; j < pn; ++j) um[si * 256 + y * pn + j] = row[j];
        } else {
            // zero lossAcc (16 f) + hist (4096 i32), contiguous
            for (int i = tid - 144; i < 4112; i += 112) ((int*)lossAcc)[i] = 0;
        }
    } else {
        int i = (blk - 161) * 1024 + tid * 4;
        float4 z = {0.f, 0.f, 0.f, 0.f};
        *(float4*)(fhat + i) = z;
    }
}

// ----------------------- per-scale kernels ---------------------------------

// area downsample of (f_input - f_hat) -> token-major fp16 hi/lo [t*32+c];
// pads tokens T..Tp with zeros; zeroes best[0..Tp)
template <int PN>
__global__ void __launch_bounds__(256) k_down(const float* __restrict__ fin,
                                              const float* __restrict__ fhat,
                                              _Float16* __restrict__ xh,
                                              _Float16* __restrict__ xl,
                                              unsigned long long* __restrict__ best) {
    constexpr int T = 128 * PN * PN;
    constexpr int Tp = ((T + 511) / 512) * 512;
    int id = blockIdx.x * 256 + threadIdx.x;
    if (id < Tp) best[id] = 0ull;
    if (id >= 32 * Tp) return;
    int t = id >> 5, c = id & 31;
    if (t >= T) { xh[id] = (_Float16)0.f; xl[id] = (_Float16)0.f; return; }
    int b = t / (PN * PN), r = t % (PN * PN), oy = r / PN, ox = r % PN;
    int sy = oy * 16 / PN, ey = ((oy + 1) * 16 + PN - 1) / PN;
    int sx = ox * 16 / PN, ex = ((ox + 1) * 16 + PN - 1) / PN;
    float wy = 1.f / (float)(ey - sy);
    float wx = 1.f / (float)(ex - sx);
    const float* pi = fin + b * 8192 + c * 256;
    const float* ph = fhat + b * 8192 + c * 256;
    float s = 0.f;
    for (int y = sy; y < ey; ++y)
        for (int x = sx; x < ex; ++x)
            s += pi[y * 16 + x] - ph[y * 16 + x];
    float v = s * (wy * wx);
    _Float16 h = (_Float16)v;
    xh[id] = h;
    xl[id] = (_Float16)(v - (float)h);
}

// MFMA cosine argmax. Block = 4 waves; wave = 128 tokens (8 M-tiles).
// Codes split into SEG segments across blocks; chunk of CH codes in LDS.
template <int PN, int SEG>
__global__ void __launch_bounds__(256, 2) k_quant(
        const half8* __restrict__ xh, const half8* __restrict__ xl,
        const float4* __restrict__ cbh4, const float4* __restrict__ cbl4,
        unsigned long long* __restrict__ best) {
    constexpr int T = 128 * PN * PN;
    constexpr int Tp = ((T + 511) / 512) * 512;
    constexpr int TB = Tp / 512;
    constexpr int CPS = 4096 / SEG;                 // codes per segment
    constexpr int CH = (CPS < 128) ? CPS : 128;     // codes staged per chunk
    __shared__ __align__(16) _Float16 sh[CH * 40];  // stride 40 halfs (80B)
    __shared__ __align__(16) _Float16 sl[CH * 40];

    int tid = threadIdx.x;
    int bt = blockIdx.x % TB, seg = blockIdx.x / TB;
    int wv = tid >> 6, lane = tid & 63;
    int n0 = lane & 15, g = lane >> 4;
    int tokbase = bt * 512 + wv * 128;

    half8 ah[8], al[8];
#pragma unroll
    for (int mt = 0; mt < 8; ++mt) {
        int tok = tokbase + mt * 16 + n0;
        ah[mt] = xh[tok * 4 + g];
        al[mt] = xl[tok * 4 + g];
    }

    float mx[8][4];
    unsigned ib[8][4];
#pragma unroll
    for (int mt = 0; mt < 8; ++mt)
#pragma unroll
        for (int r = 0; r < 4; ++r) { mx[mt][r] = -3.0e38f; ib[mt][r] = 0u; }

    const floatx4 z4 = {0.f, 0.f, 0.f, 0.f};
    int cbase = seg * CPS;
    for (int cc0 = 0; cc0 < CPS; cc0 += CH) {
        __syncthreads();
        for (int e = tid; e < CH * 4; e += 256) {   // stage chunk (hi+lo)
            int code = e >> 2, q = e & 3;
            *(float4*)(sh + code * 40 + q * 8) = cbh4[(cbase + cc0 + code) * 4 + q];
            *(float4*)(sl + code * 40 + q * 8) = cbl4[(cbase + cc0 + code) * 4 + q];
        }
        __syncthreads();
#pragma unroll 2
        for (int nt = 0; nt < CH / 16; ++nt) {
            half8 bh = *(const half8*)(sh + (nt * 16 + n0) * 40 + g * 8);
            half8 bl = *(const half8*)(sl + (nt * 16 + n0) * 40 + g * 8);
            unsigned colb = (unsigned)(cbase + cc0 + nt * 16);
#pragma unroll
            for (int mt = 0; mt < 8; ++mt) {
                floatx4 c;
                c = __builtin_amdgcn_mfma_f32_16x16x32_f16(ah[mt], bh, z4, 0, 0, 0);
                c = __builtin_amdgcn_mfma_f32_16x16x32_f16(al[mt], bh, c,  0, 0, 0);
                c = __builtin_amdgcn_mfma_f32_16x16x32_f16(ah[mt], bl, c,  0, 0, 0);
#pragma unroll
                for (int r = 0; r < 4; ++r) {
                    bool gt = c[r] > mx[mt][r];
                    mx[mt][r] = gt ? c[r] : mx[mt][r];
                    ib[mt][r] = gt ? colb : ib[mt][r];
                }
            }
        }
    }

#pragma unroll
    for (int mt = 0; mt < 8; ++mt) {
#pragma unroll
        for (int r = 0; r < 4; ++r) {
            unsigned long long k = packSI(mx[mt][r], ib[mt][r] + (unsigned)n0);
            unsigned long long o;
            o = shflx(k, 1); k = (o > k) ? o : k;
            o = shflx(k, 2); k = (o > k) ? o : k;
            o = shflx(k, 4); k = (o > k) ? o : k;
            o = shflx(k, 8); k = (o > k) ? o : k;
            if (n0 == 0)
                atomicMax(best + (tokbase + mt * 16 + g * 4 + r), k);
        }
    }
}

// gather codes -> bicubic upsample -> 3x3 conv (phi) -> f_hat update + loss.
// grid 512 = (image, quarter of 4 rows); 256 threads.
// conv phase: wave = ic-group of 8, lane = pixel (64 px/quarter).
// epilogue: lane = (16 px) x (4 oc-groups of 8), all 4 waves active.
template <int PN, int K, bool LAST>
__global__ void __launch_bounds__(256) k_conv(const float* __restrict__ fin,
                                              float* __restrict__ fhat,
                                              const float* __restrict__ cbook,
                                              const unsigned long long* __restrict__ best,
                                              const float* __restrict__ wT,
                                              const float* __restrict__ phib,
                                              const float* __restrict__ um,
                                              float* __restrict__ lossAcc,
                                              int* __restrict__ hist,
                                              float* __restrict__ dout) {
    constexpr int NT = PN * PN;  // tokens per image
    // regionA: h0 [NT*32 floats] (phases 1-2), then partial [4*64*33] (5-6)
    __shared__ __align__(16) float regionA[4 * 64 * 33];
    __shared__ float hu[32 * 6 * 18];                  // [c][ry][x+1]
    __shared__ float hu1[(PN < 16) ? 32 * 6 * PN : 1]; // [c][ry][i]
    __shared__ float Us[(PN < 16) ? 16 * PN : 1];
    __shared__ int idxs[(PN < 16) ? NT : 96];
    __shared__ float red[4];

    int b = blockIdx.x >> 2, q = blockIdx.x & 3;
    int y0 = q * 4;
    int ylo = (q == 0) ? 0 : y0 - 1;
    int yhi = (q == 3) ? 15 : y0 + 4;
    int nrows = yhi - ylo + 1;                         // 5 or 6
    int tid = threadIdx.x;
    float* h0 = regionA;
    float* partial = regionA;

    if (PN < 16) {
        for (int e = tid; e < NT; e += 256) idxs[e] = unpackI(best[b * NT + e]);
        for (int e = tid; e < 16 * PN; e += 256) Us[e] = um[e];
    } else {
        for (int e = tid; e < nrows * 16; e += 256)
            idxs[e] = unpackI(best[b * 256 + ylo * 16 + e]);
    }
    __syncthreads();

    if (PN < 16) {
        for (int e = tid; e < NT * 32; e += 256) {
            int tk = e >> 5, c = e & 31;
            h0[e] = cbook[idxs[tk] * 32 + c];
        }
        __syncthreads();
        // y-pass: hu1[c][ry][i] = sum_j U[ylo+ry][j] * h0[j*PN+i][c]
        for (int e = tid; e < nrows * PN * 32; e += 256) {
            int ryi = e >> 5, c = e & 31;
            int ry = ryi / PN, i = ryi % PN;
            int yy = ylo + ry;
            float s = 0.f;
            for (int j = 0; j < PN; ++j) s += Us[yy * PN + j] * h0[(j * PN + i) * 32 + c];
            hu1[(c * 6 + ry) * PN + i] = s;
        }
        __syncthreads();
        // x-pass: hu[c][ry][x+1] = sum_i U[x][i] * hu1[c][ry][i]
        for (int e = tid; e < 32 * nrows * 16; e += 256) {
            int cr = e >> 4, x = e & 15;
            int c = cr / 6, ry = cr % 6;
            if (ry >= nrows) { c = cr / nrows; ry = cr % nrows; }  // dense pack
            // recompute densely: e enumerates c-major over nrows rows
            c = e / (nrows * 16);
            int r2 = e % (nrows * 16);
            ry = r2 >> 4; x = r2 & 15;
            float s = 0.f;
            for (int i = 0; i < PN; ++i) s += Us[x * PN + i] * hu1[(c * 6 + ry) * PN + i];
            hu[(c * 6 + ry) * 18 + x + 1] = s;
        }
    } else {
        for (int e = tid; e < 32 * nrows * 16; e += 256) {
            int c = e / (nrows * 16);
            int r2 = e % (nrows * 16);
            int ry = r2 >> 4, xx = r2 & 15;
            hu[(c * 6 + ry) * 18 + xx + 1] = cbook[idxs[ry * 16 + xx] * 32 + c];
        }
    }
    for (int e = tid; e < 32 * 6; e += 256) {  // zero-pad columns
        hu[e * 18 + 0] = 0.f;
        hu[e * 18 + 17] = 0.f;
    }
    __syncthreads();

    // conv: wave wv handles ic = wv*8..wv*8+7 for all 64 px of the quarter
    int wv = tid >> 6, lane = tid & 63;
    int row = lane >> 4, y = y0 + row, x = lane & 15;
    float acc[32];
#pragma unroll
    for (int o = 0; o < 32; ++o) acc[o] = 0.f;
    const float* wk = wT + K * 9216;
#pragma unroll
    for (int ii = 0; ii < 8; ++ii) {
        int ic = wv * 8 + ii;
#pragma unroll
        for (int ky = 0; ky < 3; ++ky) {
            int gy = y + ky - 1;
            bool ok = (gy >= 0) & (gy <= 15);
            int ry = ok ? (gy - ylo) : 0;
            const float* hrow = hu + (ic * 6 + ry) * 18 + x;
            float hv0 = ok ? hrow[0] : 0.f;
            float hv1 = ok ? hrow[1] : 0.f;
            float hv2 = ok ? hrow[2] : 0.f;
            int sb = __builtin_amdgcn_readfirstlane(ic * 9 + ky * 3) * 32;
            const float* w0 = wk + sb;
#pragma unroll
            for (int o = 0; o < 32; ++o) {
                acc[o] = fmaf(w0[o],      hv0, acc[o]);
                acc[o] = fmaf(w0[32 + o], hv1, acc[o]);
                acc[o] = fmaf(w0[64 + o], hv2, acc[o]);
            }
        }
    }
    __syncthreads();   // h0 reads long done; regionA now = partial
#pragma unroll
    for (int o = 0; o < 32; ++o) partial[(wv * 64 + lane) * 33 + o] = acc[o];
    __syncthreads();

    // epilogue: lane = pxl (w*16 + l&15), oc-group = l>>4
    float ss = 0.f;
    {
        int pxl = wv * 16 + (lane & 15);
        int ocq = lane >> 4;
        int erow = pxl >> 4, ey2 = y0 + erow, ex2 = pxl & 15;
        int ryc = ey2 - ylo;
        int gbase = b * 8192 + ey2 * 16 + ex2;
        const float* bias = phib + K * 32;
#pragma unroll
        for (int oi = 0; oi < 8; ++oi) {
            int o = ocq * 8 + oi;
            float conv = partial[(0 * 64 + pxl) * 33 + o]
                       + partial[(1 * 64 + pxl) * 33 + o]
                       + partial[(2 * 64 + pxl) * 33 + o]
                       + partial[(3 * 64 + pxl) * 33 + o] + bias[o];
            float hval = 0.5f * hu[(o * 6 + ryc) * 18 + ex2 + 1] + 0.5f * conv;
            float fh = fhat[gbase + o * 256] + hval;
            fhat[gbase + o * 256] = fh;
            if (LAST) dout[gbase + o * 256] = fh;
            float d = fh - fin[gbase + o * 256];
            ss = fmaf(d, d, ss);
        }
    }
    if (LAST && tid < 64) {  // histogram of this quarter's own tokens
        int idx_own = idxs[(y0 - ylo) * 16 + tid];
        atomicAdd(hist + idx_own, 1);
    }
    // loss reduction: wave shuffle, then cross-wave via red[]
#pragma unroll
    for (int m = 1; m < 64; m <<= 1) ss += __shfl_xor(ss, m, 64);
    if (lane == 0) red[wv] = ss;
    __syncthreads();
    if (tid == 0) atomicAdd(lossAcc, red[0] + red[1] + red[2] + red[3]);
}

__global__ void __launch_bounds__(256) k_final(const float* __restrict__ lossAcc,
                                               const int* __restrict__ hist,
                                               float* __restrict__ out) {
    __shared__ float red[256];
    int tid = threadIdx.x;
    float s = 0.f;
    for (int i = tid; i < 4096; i += 256) {
        float p = (float)hist[i] * (1.f / 32768.f);
        s += p * logf(p + 1e-10f);
    }
    red[tid] = s;
    __syncthreads();
    for (int k = 128; k > 0; k >>= 1) {
        if (tid < k) red[tid] += red[tid + k];
        __syncthreads();
    }
    if (tid == 0) {
        out[1048577] = expf(-red[0]);
        float L = 0.f;
        for (int si = 0; si < 10; ++si) L += lossAcc[si];
        out[1048576] = L * 1.25f / 1048576.f * 0.1f;
    }
}

// ------------------------------ launch -------------------------------------

extern "C" void kernel_launch(void* const* d_in, const int* in_sizes, int n_in,
                              void* d_out, int out_size, void* d_ws, size_t ws_size,
                              hipStream_t stream) {
    const float* f_in  = (const float*)d_in[0];   // [128,32,16,16]
    const float* cbook = (const float*)d_in[1];   // [4096,32]
    const float* phiw  = (const float*)d_in[2];   // [4,32,32,3,3]
    const float* phib  = (const float*)d_in[3];   // [4,32]
    float* out = (float*)d_out;
    char* base = (char*)d_ws;

    float* fhat    = (float*)(base);                       // 4,194,304 B
    float* lossAcc = (float*)(base + 4194304);             // 64 B
    int*   hist    = (int*)  (base + 4194368);             // 16,384 B
    float* wT      = (float*)(base + 4210752);             // 147,456 B
    float* um      = (float*)(base + 4358208);             // 9,216 B
    _Float16* cbh  = (_Float16*)(base + 4367424);          // 262,144 B
    _Float16* cbl  = (_Float16*)(base + 4629568);          // 262,144 B
    _Float16* xh   = (_Float16*)(base + 4891712);          // 2,097,152 B
    _Float16* xl   = (_Float16*)(base + 6988864);          // 2,097,152 B
    unsigned long long* best = (unsigned long long*)(base + 9086016);  // 262,144 B

    k_setup<<<1185, 256, 0, stream>>>(cbook, phiw, cbh, cbl, wT, um, fhat, lossAcc);

#define SCALE(SI, PN, SEG, K, LAST)                                                    \
    {                                                                                  \
        constexpr int T = 128 * PN * PN;                                               \
        constexpr int Tp = ((T + 511) / 512) * 512;                                    \
        constexpr int TB = Tp / 512;                                                   \
        k_down<PN><<<(Tp * 32) / 256, 256, 0, stream>>>(f_in, fhat, xh, xl, best);     \
        k_quant<PN, SEG><<<TB * SEG, 256, 0, stream>>>(                                \
            (const half8*)xh, (const half8*)xl, (const float4*)cbh,                    \
            (const float4*)cbl, best);                                                 \
        k_conv<PN, K, LAST><<<512, 256, 0, stream>>>(f_in, fhat, cbook, best, wT,      \
                                                     phib, um + SI * 256,              \
                                                     lossAcc + SI, hist, out);         \
    }
    SCALE(0, 1, 256, 0, false);
    SCALE(1, 2, 256, 0, false);
    SCALE(2, 3, 128, 0, false);
    SCALE(3, 4, 128, 1, false);
    SCALE(4, 5, 128, 1, false);
    SCALE(5, 6, 128, 2, false);
    SCALE(6, 8, 128, 2, false);
    SCALE(7, 10, 64, 2, false);
    SCALE(8, 13, 64, 3, false);
    SCALE(9, 16, 32, 3, true);
#undef SCALE
    k_final<<<1, 256, 0, stream>>>(lossAcc, hist, out);
}

// Round 4
// 905.102 us; speedup vs baseline: 1.8373x; 1.8373x over previous
//
#include <hip/hip_runtime.h>
#include <stdint.h>
#include <math.h>

// ---------------------------------------------------------------------------
// MultiScaleResidualQuantizer3D  (B=128, C=32, HW=16, N_E=4096, 10 scales)
// Round 4: conv reverted to round-2 shape (half-image blocks, grid 256) but
//   split by OC not IC: no partial[] LDS, fewer barriers, halved scalar-weight
//   live range per wave. Quant SEG rebalanced (occupancy vs atomicMax count).
//   - scoring: MFMA fp16 3-term split (xh*ch + xl*ch + xh*cl), fp32 acc
//   - PHI_IDX = [0,0,0,1,1,2,2,2,3,3] (exact np.linspace tie resolution)
// ---------------------------------------------------------------------------

#define DEVI __device__ __forceinline__

static constexpr int NE = 4096;

typedef _Float16 half8 __attribute__((ext_vector_type(8)));
typedef float floatx4 __attribute__((ext_vector_type(4)));

DEVI unsigned fkey(float f) {
    unsigned u = __float_as_uint(f);
    return (u & 0x80000000u) ? ~u : (u | 0x80000000u);  // order-preserving
}
DEVI unsigned long long packSI(float s, unsigned idx) {
    // high: monotone score key; low: ~idx so ties prefer SMALLER idx (first max)
    return ((unsigned long long)fkey(s) << 32) | (unsigned)(~idx);
}
DEVI int unpackI(unsigned long long v) {
    return (int)(~(unsigned)(v & 0xFFFFFFFFull));
}
DEVI unsigned long long shflx(unsigned long long v, int m) {
    unsigned lo = (unsigned)v, hi = (unsigned)(v >> 32);
    lo = __shfl_xor(lo, m, 64);
    hi = __shfl_xor(hi, m, 64);
    return ((unsigned long long)hi << 32) | lo;
}

// --------------------------- setup kernel ----------------------------------
// blocks 0..15: codebook normalize + fp16 hi/lo split
// blocks 16..159: wT transpose  wT[k][(ic*9+ky*3+kx)][oc]
// block 160: bicubic U matrices (f64 math) + zero lossAcc/hist
// blocks 161..1184: zero fhat
__global__ void __launch_bounds__(256) k_setup(const float* __restrict__ cb,
                                               const float* __restrict__ pw,
                                               _Float16* __restrict__ cbh,
                                               _Float16* __restrict__ cbl,
                                               float* __restrict__ wT,
                                               float* __restrict__ um,
                                               float* __restrict__ fhat,
                                               float* __restrict__ lossAcc) {
    int blk = blockIdx.x, tid = threadIdx.x;
    if (blk < 16) {
        int r = blk * 256 + tid;
        const float* src = cb + r * 32;
        float v[32];
        float ss = 0.f;
#pragma unroll
        for (int j = 0; j < 32; ++j) { v[j] = src[j]; ss += v[j] * v[j]; }
        float n = fmaxf(sqrtf(ss), 1e-12f);
#pragma unroll
        for (int j = 0; j < 32; ++j) {
            float x = v[j] / n;
            _Float16 h = (_Float16)x;
            cbh[r * 32 + j] = h;
            cbl[r * 32 + j] = (_Float16)(x - (float)h);
        }
    } else if (blk < 160) {
        int e = (blk - 16) * 256 + tid;             // < 36864
        int k = e / 9216, rem = e % 9216;
        int s = rem / 32, oc = rem % 32;
        int ic = s / 9, k9 = s % 9, ky = k9 / 3, kx = k9 % 3;
        wT[e] = pw[(((k * 32 + oc) * 32 + ic) * 3 + ky) * 3 + kx];
    } else if (blk == 160) {
        if (tid < 144) {
            const int pns[9] = {1, 2, 3, 4, 5, 6, 8, 10, 13};
            int si = tid / 16, y = tid % 16, pn = pns[si];
            double scale = (double)pn / 16.0;
            double src = ((double)y + 0.5) * scale - 0.5;
            double fl = floor(src);
            int i0 = (int)fl;
            double f = src - fl;
            float row[13];
            for (int j = 0; j < pn; ++j) row[j] = 0.f;
            const double a = -0.75;
#pragma unroll
            for (int off = -1; off <= 2; ++off) {
                double t2 = fabs(f - (double)off);
                double wgt;
                if (t2 <= 1.0)      wgt = ((a + 2.0) * t2 - (a + 3.0)) * t2 * t2 + 1.0;
                else if (t2 < 2.0)  wgt = (((t2 - 5.0) * t2 + 8.0) * t2 - 4.0) * a;
                else                wgt = 0.0;
                int j = i0 + off;
                j = j < 0 ? 0 : (j > pn - 1 ? pn - 1 : j);
                row[j] = (float)((double)row[j] + wgt);   // numpy f32 += f64
            }
            for (int j = 0; j < pn; ++j) um[si * 256 + y * pn + j] = row[j];
        } else {
            // zero lossAcc (16 f) + hist (4096 i32), contiguous
            for (int i = tid - 144; i < 4112; i += 112) ((int*)lossAcc)[i] = 0;
        }
    } else {
        int i = (blk - 161) * 1024 + tid * 4;
        float4 z = {0.f, 0.f, 0.f, 0.f};
        *(float4*)(fhat + i) = z;
    }
}

// ----------------------- per-scale kernels ---------------------------------

// area downsample of (f_input - f_hat) -> token-major fp16 hi/lo [t*32+c];
// pads tokens T..Tp with zeros; zeroes best[0..Tp)
template <int PN>
__global__ void __launch_bounds__(256) k_down(const float* __restrict__ fin,
                                              const float* __restrict__ fhat,
                                              _Float16* __restrict__ xh,
                                              _Float16* __restrict__ xl,
                                              unsigned long long* __restrict__ best) {
    constexpr int T = 128 * PN * PN;
    constexpr int Tp = ((T + 511) / 512) * 512;
    int id = blockIdx.x * 256 + threadIdx.x;
    if (id < Tp) best[id] = 0ull;
    if (id >= 32 * Tp) return;
    int t = id >> 5, c = id & 31;
    if (t >= T) { xh[id] = (_Float16)0.f; xl[id] = (_Float16)0.f; return; }
    int b = t / (PN * PN), r = t % (PN * PN), oy = r / PN, ox = r % PN;
    int sy = oy * 16 / PN, ey = ((oy + 1) * 16 + PN - 1) / PN;
    int sx = ox * 16 / PN, ex = ((ox + 1) * 16 + PN - 1) / PN;
    float wy = 1.f / (float)(ey - sy);
    float wx = 1.f / (float)(ex - sx);
    const float* pi = fin + b * 8192 + c * 256;
    const float* ph = fhat + b * 8192 + c * 256;
    float s = 0.f;
    for (int y = sy; y < ey; ++y)
        for (int x = sx; x < ex; ++x)
            s += pi[y * 16 + x] - ph[y * 16 + x];
    float v = s * (wy * wx);
    _Float16 h = (_Float16)v;
    xh[id] = h;
    xl[id] = (_Float16)(v - (float)h);
}

// MFMA cosine argmax. Block = 4 waves; wave = 128 tokens (8 M-tiles).
// Codes split into SEG segments across blocks; chunk of CH codes in LDS.
template <int PN, int SEG>
__global__ void __launch_bounds__(256, 2) k_quant(
        const half8* __restrict__ xh, const half8* __restrict__ xl,
        const float4* __restrict__ cbh4, const float4* __restrict__ cbl4,
        unsigned long long* __restrict__ best) {
    constexpr int T = 128 * PN * PN;
    constexpr int Tp = ((T + 511) / 512) * 512;
    constexpr int TB = Tp / 512;
    constexpr int CPS = 4096 / SEG;                 // codes per segment
    constexpr int CH = (CPS < 128) ? CPS : 128;     // codes staged per chunk
    __shared__ __align__(16) _Float16 sh[CH * 40];  // stride 40 halfs (80B)
    __shared__ __align__(16) _Float16 sl[CH * 40];

    int tid = threadIdx.x;
    int bt = blockIdx.x % TB, seg = blockIdx.x / TB;
    int wv = tid >> 6, lane = tid & 63;
    int n0 = lane & 15, g = lane >> 4;
    int tokbase = bt * 512 + wv * 128;

    half8 ah[8], al[8];
#pragma unroll
    for (int mt = 0; mt < 8; ++mt) {
        int tok = tokbase + mt * 16 + n0;
        ah[mt] = xh[tok * 4 + g];
        al[mt] = xl[tok * 4 + g];
    }

    float mx[8][4];
    unsigned ib[8][4];
#pragma unroll
    for (int mt = 0; mt < 8; ++mt)
#pragma unroll
        for (int r = 0; r < 4; ++r) { mx[mt][r] = -3.0e38f; ib[mt][r] = 0u; }

    const floatx4 z4 = {0.f, 0.f, 0.f, 0.f};
    int cbase = seg * CPS;
    for (int cc0 = 0; cc0 < CPS; cc0 += CH) {
        __syncthreads();
        for (int e = tid; e < CH * 4; e += 256) {   // stage chunk (hi+lo)
            int code = e >> 2, q = e & 3;
            *(float4*)(sh + code * 40 + q * 8) = cbh4[(cbase + cc0 + code) * 4 + q];
            *(float4*)(sl + code * 40 + q * 8) = cbl4[(cbase + cc0 + code) * 4 + q];
        }
        __syncthreads();
#pragma unroll 2
        for (int nt = 0; nt < CH / 16; ++nt) {
            half8 bh = *(const half8*)(sh + (nt * 16 + n0) * 40 + g * 8);
            half8 bl = *(const half8*)(sl + (nt * 16 + n0) * 40 + g * 8);
            unsigned colb = (unsigned)(cbase + cc0 + nt * 16);
#pragma unroll
            for (int mt = 0; mt < 8; ++mt) {
                floatx4 c;
                c = __builtin_amdgcn_mfma_f32_16x16x32_f16(ah[mt], bh, z4, 0, 0, 0);
                c = __builtin_amdgcn_mfma_f32_16x16x32_f16(al[mt], bh, c,  0, 0, 0);
                c = __builtin_amdgcn_mfma_f32_16x16x32_f16(ah[mt], bl, c,  0, 0, 0);
#pragma unroll
                for (int r = 0; r < 4; ++r) {
                    bool gt = c[r] > mx[mt][r];
                    mx[mt][r] = gt ? c[r] : mx[mt][r];
                    ib[mt][r] = gt ? colb : ib[mt][r];
                }
            }
        }
    }

#pragma unroll
    for (int mt = 0; mt < 8; ++mt) {
#pragma unroll
        for (int r = 0; r < 4; ++r) {
            unsigned long long k = packSI(mx[mt][r], ib[mt][r] + (unsigned)n0);
            unsigned long long o;
            o = shflx(k, 1); k = (o > k) ? o : k;
            o = shflx(k, 2); k = (o > k) ? o : k;
            o = shflx(k, 4); k = (o > k) ? o : k;
            o = shflx(k, 8); k = (o > k) ? o : k;
            if (n0 == 0)
                atomicMax(best + (tokbase + mt * 16 + g * 4 + r), k);
        }
    }
}

// gather codes -> bicubic upsample -> 3x3 conv (phi) -> f_hat update + loss.
// grid 256 = (image, half of 8 rows); 256 threads = (128 px, 2 oc-halves).
// Each thread: all 32 ic, 16 oc -> no cross-thread partial needed.
template <int PN, int K, bool LAST>
__global__ void __launch_bounds__(256) k_conv(const float* __restrict__ fin,
                                              float* __restrict__ fhat,
                                              const float* __restrict__ cbook,
                                              const unsigned long long* __restrict__ best,
                                              const float* __restrict__ wT,
                                              const float* __restrict__ phib,
                                              const float* __restrict__ um,
                                              float* __restrict__ lossAcc,
                                              int* __restrict__ hist,
                                              float* __restrict__ dout) {
    constexpr int NR = 9;        // rows staged: half (8) + halo (1, edge-clipped)
    constexpr int NT = PN * PN;  // tokens per image
    __shared__ float h0[NT * 32];                      // [token][c]
    __shared__ float hu[32 * NR * 18];                 // [c][ry][x+1], padded cols
    __shared__ float hu1[(PN < 16) ? 32 * NR * PN : 1];
    __shared__ float Us[(PN < 16) ? 16 * PN : 1];
    __shared__ int idxs[NT];
    __shared__ float red[4];

    int b = blockIdx.x >> 1, half = blockIdx.x & 1;
    int y0 = half * 8, ylo = half ? 7 : 0;
    int tid = threadIdx.x;

    for (int e = tid; e < NT; e += 256) idxs[e] = unpackI(best[b * NT + e]);
    if (PN < 16)
        for (int e = tid; e < 16 * PN; e += 256) Us[e] = um[e];
    __syncthreads();

    for (int e = tid; e < NT * 32; e += 256) {
        int tk = e >> 5, c = e & 31;
        h0[e] = cbook[idxs[tk] * 32 + c];
    }
    __syncthreads();

    if (PN < 16) {
        // y-pass: hu1[c][ry][i] = sum_j U[ylo+ry][j] * h0[j*PN+i][c]
        for (int e = tid; e < NR * PN * 32; e += 256) {
            int ryi = e >> 5, c = e & 31;
            int ry = ryi / PN, i = ryi % PN;
            int yy = ylo + ry;
            float s = 0.f;
            for (int j = 0; j < PN; ++j) s += Us[yy * PN + j] * h0[(j * PN + i) * 32 + c];
            hu1[(c * NR + ry) * PN + i] = s;
        }
        __syncthreads();
        // x-pass: hu[c][ry][x+1] = sum_i U[x][i] * hu1[c][ry][i]
        for (int e = tid; e < 32 * NR * 16; e += 256) {
            int c = e / 144, r2 = e % 144;
            int ry = r2 >> 4, x = r2 & 15;
            float s = 0.f;
            for (int i = 0; i < PN; ++i) s += Us[x * PN + i] * hu1[(c * NR + ry) * PN + i];
            hu[(c * NR + ry) * 18 + x + 1] = s;
        }
    } else {
        for (int e = tid; e < 32 * NR * 16; e += 256) {
            int c = e / 144, r2 = e % 144;
            int ry = r2 >> 4, xx = r2 & 15;
            hu[(c * NR + ry) * 18 + xx + 1] = h0[((ylo + ry) * 16 + xx) * 32 + c];
        }
    }
    for (int e = tid; e < 32 * NR; e += 256) {  // zero-pad columns
        hu[e * 18 + 0] = 0.f;
        hu[e * 18 + 17] = 0.f;
    }
    __syncthreads();

    // conv: thread = (pixel, oc-half); all 32 ic; weights via wave-uniform
    // scalar loads (48-dword live range per group).
    int px = tid & 127, ocq = tid >> 7;
    int row = px >> 4, y = y0 + row, x = px & 15;
    float acc[16];
#pragma unroll
    for (int o = 0; o < 16; ++o) acc[o] = 0.f;
    const float* wk = wT + K * 9216 + ocq * 16;
    for (int ic = 0; ic < 32; ++ic) {
#pragma unroll
        for (int ky = 0; ky < 3; ++ky) {
            int gy = y + ky - 1;
            if (gy < 0 || gy > 15) continue;  // zero padding rows
            int ry = gy - ylo;
            const float* hrow = hu + (ic * NR + ry) * 18 + x;  // window x..x+2
            float hv0 = hrow[0], hv1 = hrow[1], hv2 = hrow[2];
            int sb = __builtin_amdgcn_readfirstlane(ic * 9 + ky * 3) * 32;
            const float* w0 = wk + sb;
#pragma unroll
            for (int o = 0; o < 16; ++o) {
                acc[o] = fmaf(w0[o],      hv0, acc[o]);
                acc[o] = fmaf(w0[32 + o], hv1, acc[o]);
                acc[o] = fmaf(w0[64 + o], hv2, acc[o]);
            }
        }
    }

    // epilogue: each thread owns its 16 oc outputs at its pixel
    float ss = 0.f;
    {
        const float* bias = phib + K * 32 + ocq * 16;
        int gidx = b * 8192 + (ocq * 16) * 256 + y * 16 + x;
        int ryc = y - ylo;
#pragma unroll
        for (int oi = 0; oi < 16; ++oi) {
            int o = ocq * 16 + oi;
            float conv = acc[oi] + bias[oi];
            float hval = 0.5f * hu[(o * NR + ryc) * 18 + x + 1] + 0.5f * conv;
            float fh = fhat[gidx + oi * 256] + hval;
            fhat[gidx + oi * 256] = fh;
            if (LAST) dout[gidx + oi * 256] = fh;
            float d = fh - fin[gidx + oi * 256];
            ss = fmaf(d, d, ss);
        }
    }
    if (LAST && tid < 128)  // histogram of this half's own tokens (PN==16)
        atomicAdd(hist + idxs[half * 128 + tid], 1);

    // loss reduction: wave shuffle, then cross-wave via red[]
    int wv = tid >> 6, lane = tid & 63;
#pragma unroll
    for (int m = 1; m < 64; m <<= 1) ss += __shfl_xor(ss, m, 64);
    if (lane == 0) red[wv] = ss;
    __syncthreads();
    if (tid == 0) atomicAdd(lossAcc, red[0] + red[1] + red[2] + red[3]);
}

__global__ void __launch_bounds__(256) k_final(const float* __restrict__ lossAcc,
                                               const int* __restrict__ hist,
                                               float* __restrict__ out) {
    __shared__ float red[256];
    int tid = threadIdx.x;
    float s = 0.f;
    for (int i = tid; i < 4096; i += 256) {
        float p = (float)hist[i] * (1.f / 32768.f);
        s += p * logf(p + 1e-10f);
    }
    red[tid] = s;
    __syncthreads();
    for (int k = 128; k > 0; k >>= 1) {
        if (tid < k) red[tid] += red[tid + k];
        __syncthreads();
    }
    if (tid == 0) {
        out[1048577] = expf(-red[0]);
        float L = 0.f;
        for (int si = 0; si < 10; ++si) L += lossAcc[si];
        out[1048576] = L * 1.25f / 1048576.f * 0.1f;
    }
}

// ------------------------------ launch -------------------------------------

extern "C" void kernel_launch(void* const* d_in, const int* in_sizes, int n_in,
                              void* d_out, int out_size, void* d_ws, size_t ws_size,
                              hipStream_t stream) {
    const float* f_in  = (const float*)d_in[0];   // [128,32,16,16]
    const float* cbook = (const float*)d_in[1];   // [4096,32]
    const float* phiw  = (const float*)d_in[2];   // [4,32,32,3,3]
    const float* phib  = (const float*)d_in[3];   // [4,32]
    float* out = (float*)d_out;
    char* base = (char*)d_ws;

    float* fhat    = (float*)(base);                       // 4,194,304 B
    float* lossAcc = (float*)(base + 4194304);             // 64 B
    int*   hist    = (int*)  (base + 4194368);             // 16,384 B
    float* wT      = (float*)(base + 4210752);             // 147,456 B
    float* um      = (float*)(base + 4358208);             // 9,216 B
    _Float16* cbh  = (_Float16*)(base + 4367424);          // 262,144 B
    _Float16* cbl  = (_Float16*)(base + 4629568);          // 262,144 B
    _Float16* xh   = (_Float16*)(base + 4891712);          // 2,097,152 B
    _Float16* xl   = (_Float16*)(base + 6988864);          // 2,097,152 B
    unsigned long long* best = (unsigned long long*)(base + 9086016);  // 262,144 B

    k_setup<<<1185, 256, 0, stream>>>(cbook, phiw, cbh, cbl, wT, um, fhat, lossAcc);

#define SCALE(SI, PN, SEG, K, LAST)                                                    \
    {                                                                                  \
        constexpr int T = 128 * PN * PN;                                               \
        constexpr int Tp = ((T + 511) / 512) * 512;                                    \
        constexpr int TB = Tp / 512;                                                   \
        k_down<PN><<<(Tp * 32) / 256, 256, 0, stream>>>(f_in, fhat, xh, xl, best);     \
        k_quant<PN, SEG><<<TB * SEG, 256, 0, stream>>>(                                \
            (const half8*)xh, (const half8*)xl, (const float4*)cbh,                    \
            (const float4*)cbl, best);                                                 \
        k_conv<PN, K, LAST><<<256, 256, 0, stream>>>(f_in, fhat, cbook, best, wT,      \
                                                     phib, um + SI * 256,              \
                                                     lossAcc + SI, hist, out);         \
    }
    SCALE(0, 1, 256, 0, false);
    SCALE(1, 2, 256, 0, false);
    SCALE(2, 3, 128, 0, false);
    SCALE(3, 4, 128, 1, false);
    SCALE(4, 5, 64, 1, false);
    SCALE(5, 6, 64, 2, false);
    SCALE(6, 8, 32, 2, false);
    SCALE(7, 10, 32, 2, false);
    SCALE(8, 13, 16, 3, false);
    SCALE(9, 16, 16, 3, true);
#undef SCALE
    k_final<<<1, 256, 0, stream>>>(lossAcc, hist, out);
}